// Round 3
// baseline (485.972 us; speedup 1.0000x reference)
//
#include <hip/hip_runtime.h>
#include <math.h>

#define VIEWS 8
#define SEQ 2048
#define HID 1024
#define ATT 128
#define QSCALE 0.08838834764831845f  // 128^-0.5

typedef __attribute__((ext_vector_type(8))) short short8;
typedef __attribute__((ext_vector_type(4))) float f32x4;

__device__ __forceinline__ unsigned short f2bf(float f) {
  union { float f; unsigned u; } a; a.f = f;
  unsigned r = a.u + 0x7FFF + ((a.u >> 16) & 1);  // RNE
  return (unsigned short)(r >> 16);
}

// ---------------------------------------------------------------------------
// Transpose + convert fp32 [R][C] -> bf16 [C][R].  R,C multiples of 64.
// ---------------------------------------------------------------------------
__global__ __launch_bounds__(256)
void transpose_cvt_f32_bf16(const float* __restrict__ in,
                            unsigned short* __restrict__ out, int R, int C) {
  __shared__ alignas(16) unsigned short T[64][72];
  const int tid = threadIdx.x;
  const int r0 = blockIdx.y * 64, c0 = blockIdx.x * 64;
  const int tr = tid >> 2, tc = (tid & 3) * 16;
#pragma unroll
  for (int u = 0; u < 4; ++u) {
    float4 t = *(const float4*)&in[(size_t)(r0 + tr) * C + c0 + tc + u * 4];
    T[tc + u * 4 + 0][tr] = f2bf(t.x);
    T[tc + u * 4 + 1][tr] = f2bf(t.y);
    T[tc + u * 4 + 2][tr] = f2bf(t.z);
    T[tc + u * 4 + 3][tr] = f2bf(t.w);
  }
  __syncthreads();
  const int oc = tid >> 2, orr = (tid & 3) * 16;
#pragma unroll
  for (int u = 0; u < 2; ++u)
    *(short8*)&out[(size_t)(c0 + oc) * R + r0 + orr + u * 8] =
        *(const short8*)&T[oc][orr + u * 8];
}

// Batched variant for wq/wk/wv (z selects). R=1024, C=128. grid (2,16,3).
__global__ __launch_bounds__(256)
void transpose_qkvw(const float* __restrict__ wq, const float* __restrict__ wk,
                    const float* __restrict__ wv, unsigned short* __restrict__ oq,
                    unsigned short* __restrict__ ok, unsigned short* __restrict__ ov) {
  __shared__ alignas(16) unsigned short T[64][72];
  const int z = blockIdx.z;
  const float* in = (z == 0) ? wq : (z == 1) ? wk : wv;
  unsigned short* out = (z == 0) ? oq : (z == 1) ? ok : ov;
  const int R = HID, C = ATT;
  const int tid = threadIdx.x;
  const int r0 = blockIdx.y * 64, c0 = blockIdx.x * 64;
  const int tr = tid >> 2, tc = (tid & 3) * 16;
#pragma unroll
  for (int u = 0; u < 4; ++u) {
    float4 t = *(const float4*)&in[(size_t)(r0 + tr) * C + c0 + tc + u * 4];
    T[tc + u * 4 + 0][tr] = f2bf(t.x);
    T[tc + u * 4 + 1][tr] = f2bf(t.y);
    T[tc + u * 4 + 2][tr] = f2bf(t.z);
    T[tc + u * 4 + 3][tr] = f2bf(t.w);
  }
  __syncthreads();
  const int oc = tid >> 2, orr = (tid & 3) * 16;
#pragma unroll
  for (int u = 0; u < 2; ++u)
    *(short8*)&out[(size_t)(c0 + oc) * R + r0 + orr + u * 8] =
        *(const short8*)&T[oc][orr + u * 8];
}

// ---------------------------------------------------------------------------
// Fused QKV projection, LDS-free / barrier-free direct-fragment version.
//   z in {0,1,2}: (q@wq+bq)*scale -> qh, k@wk+bk -> kh, v@wv+bv -> vhT.
// Both MFMA operands are loaded straight from global in fragment layout:
//   A: 8 consecutive fp32 per lane (2x float4), converted to bf16 in-register.
//   B: 16 B bf16 per lane from pre-transposed wT[n][k] (L1/L2-resident).
// No LDS => no barriers => loads pipeline freely across K-iterations.
// m-tile 32 (2 waves m x 2 waves n), grid (512,1,3) => 6 blocks/CU.
// ---------------------------------------------------------------------------
__global__ __launch_bounds__(256, 4)
void qkv_proj(const float* __restrict__ q, const float* __restrict__ k,
              const float* __restrict__ v, const unsigned short* __restrict__ wqT,
              const unsigned short* __restrict__ wkT,
              const unsigned short* __restrict__ wvT,
              const float* __restrict__ bq, const float* __restrict__ bk,
              const float* __restrict__ bv, unsigned short* __restrict__ qh,
              unsigned short* __restrict__ kh, unsigned short* __restrict__ vhT) {
  const int z = blockIdx.z;
  const float* A = (z == 0) ? q : (z == 1) ? k : v;
  const unsigned short* B = (z == 0) ? wqT : (z == 1) ? wkT : wvT;
  const float* bias = (z == 0) ? bq : (z == 1) ? bk : bv;
  const float scale = (z == 0) ? QSCALE : 1.0f;
  const int tid = threadIdx.x;
  const int w = tid >> 6, lane = tid & 63;
  const int l16 = lane & 15, quad = lane >> 4;
  const int mbase = blockIdx.x * 32 + (w & 1) * 16;  // 16-row slab per wave
  const int n0 = (w >> 1) * 64;                      // 64-col half per wave

  const float* arow = &A[(size_t)(mbase + l16) * HID + quad * 8];
  const unsigned short* bbase = &B[(size_t)(n0 + l16) * HID + quad * 8];

  f32x4 acc[4];
#pragma unroll
  for (int i = 0; i < 4; ++i) acc[i] = (f32x4)0.f;

#pragma unroll 2
  for (int k0 = 0; k0 < HID; k0 += 64) {
    // A fragments for ks=0 (cols k0+quad*8) and ks=1 (cols k0+32+quad*8)
    const float4 a0 = *(const float4*)&arow[k0];
    const float4 a1 = *(const float4*)&arow[k0 + 4];
    const float4 a2 = *(const float4*)&arow[k0 + 32];
    const float4 a3 = *(const float4*)&arow[k0 + 36];
    // B fragments: nt in 0..3, ks in 0..1
    short8 bfr[8];
#pragma unroll
    for (int nt = 0; nt < 4; ++nt) {
      bfr[nt * 2]     = *(const short8*)&bbase[(size_t)nt * 16 * HID + k0];
      bfr[nt * 2 + 1] = *(const short8*)&bbase[(size_t)nt * 16 * HID + k0 + 32];
    }
    short8 af0, af1;
    af0[0] = (short)f2bf(a0.x); af0[1] = (short)f2bf(a0.y);
    af0[2] = (short)f2bf(a0.z); af0[3] = (short)f2bf(a0.w);
    af0[4] = (short)f2bf(a1.x); af0[5] = (short)f2bf(a1.y);
    af0[6] = (short)f2bf(a1.z); af0[7] = (short)f2bf(a1.w);
    af1[0] = (short)f2bf(a2.x); af1[1] = (short)f2bf(a2.y);
    af1[2] = (short)f2bf(a2.z); af1[3] = (short)f2bf(a2.w);
    af1[4] = (short)f2bf(a3.x); af1[5] = (short)f2bf(a3.y);
    af1[6] = (short)f2bf(a3.z); af1[7] = (short)f2bf(a3.w);
#pragma unroll
    for (int nt = 0; nt < 4; ++nt) {
      acc[nt] = __builtin_amdgcn_mfma_f32_16x16x32_bf16(af0, bfr[nt * 2],     acc[nt], 0, 0, 0);
      acc[nt] = __builtin_amdgcn_mfma_f32_16x16x32_bf16(af1, bfr[nt * 2 + 1], acc[nt], 0, 0, 0);
    }
  }

  if (z < 2) {
    unsigned short* outp = (z == 0) ? qh : kh;
#pragma unroll
    for (int nt = 0; nt < 4; ++nt) {
      const int col = n0 + nt * 16 + l16;
      const float bvv = bias[col];
#pragma unroll
      for (int reg = 0; reg < 4; ++reg) {
        const int row = mbase + quad * 4 + reg;
        outp[(size_t)row * ATT + col] = f2bf((acc[nt][reg] + bvv) * scale);
      }
    }
  } else {
    // transposed store: vhT[vi][a][s]; 4 consecutive rows share vi (32 | 2048)
    const int gr = mbase + quad * 4;
    const int vi = gr >> 11, s = gr & (SEQ - 1);
#pragma unroll
    for (int nt = 0; nt < 4; ++nt) {
      const int col = n0 + nt * 16 + l16;
      const float bvv = bias[col];
      ushort4 pk;
      pk.x = f2bf(acc[nt][0] + bvv);
      pk.y = f2bf(acc[nt][1] + bvv);
      pk.z = f2bf(acc[nt][2] + bvv);
      pk.w = f2bf(acc[nt][3] + bvv);
      *(ushort4*)&vhT[((size_t)vi * ATT + col) * SEQ + s] = pk;
    }
  }
}

// ---------------------------------------------------------------------------
// Fused flash attention + post-softmax-bias@V, min-2-phase pipelined:
//   per iter: ds_write tile t (from regs) -> barrier -> issue loads t+1 ->
//   compute tile t.  Loads for t+1 fly under the MFMA phase (T14/T3-min).
// grid (VIEWS, SEQ/64); LDS = 96 KB -> 1 block/CU.
// ---------------------------------------------------------------------------
__global__ __launch_bounds__(256, 1)
void flash_fused(const unsigned short* __restrict__ qh,
                 const unsigned short* __restrict__ kh,
                 const unsigned short* __restrict__ vhT,
                 const float* __restrict__ ab,
                 unsigned short* __restrict__ xbf) {
  __shared__ alignas(16) unsigned short Qs[64][136];
  __shared__ alignas(16) unsigned short Ks[2][64][136];
  __shared__ alignas(16) unsigned short VTs[2][128][72];
  __shared__ alignas(16) unsigned short Ps[64][72];
  const int tid = threadIdx.x;
  const int vi = blockIdx.x;
  const int q0 = blockIdx.y * 64;
  const int w = tid >> 6, lane = tid & 63;
  const int l16 = lane & 15, quad = lane >> 4;
  const int wb = w * 16;

  // staging coordinates
  const int kr_ = tid >> 2, kc_ = (tid & 3) * 32;   // K tile [64 keys][128]
  const int vr_ = tid >> 1, vc_ = (tid & 1) * 32;   // V^T tile [128 a][64 keys]
  const unsigned short* kbase = &kh[((size_t)vi * SEQ + kr_) * ATT + kc_];
  const unsigned short* vbase = &vhT[((size_t)vi * ATT + vr_) * SEQ + vc_];

  {  // stage Q tile once
    const int r = tid >> 2, c = (tid & 3) * 32;
    const unsigned short* src = &qh[((size_t)vi * SEQ + q0 + r) * ATT + c];
#pragma unroll
    for (int u = 0; u < 4; ++u)
      *(short8*)&Qs[r][c + u * 8] = *(const short8*)&src[u * 8];
  }

  // prologue: issue K/V loads for tile 0 into regs
  short8 krg[4], vrg[4];
#pragma unroll
  for (int u = 0; u < 4; ++u) krg[u] = *(const short8*)&kbase[u * 8];
#pragma unroll
  for (int u = 0; u < 4; ++u) vrg[u] = *(const short8*)&vbase[u * 8];

  __syncthreads();  // Qs visible
  short8 aF[4];
#pragma unroll
  for (int ks = 0; ks < 4; ++ks)
    aF[ks] = *(const short8*)&Qs[wb + l16][ks * 32 + quad * 8];

  float l_r[4] = {0.f, 0.f, 0.f, 0.f};
  f32x4 o[8], o2[8];
#pragma unroll
  for (int i = 0; i < 8; ++i) { o[i] = (f32x4)0.f; o2[i] = (f32x4)0.f; }

  const float* abrow = &ab[((size_t)vi * SEQ + q0 + wb + l16) * SEQ];

  for (int t = 0; t < SEQ / 64; ++t) {
    const int kt = t * 64;
    const int cur = t & 1;
    // bias fragment loads for tile t (issued early, consumed in PV phase)
    float4 abv[4];
    abv[0] = *(const float4*)&abrow[kt + quad * 8];
    abv[1] = *(const float4*)&abrow[kt + quad * 8 + 4];
    abv[2] = *(const float4*)&abrow[kt + 32 + quad * 8];
    abv[3] = *(const float4*)&abrow[kt + 32 + quad * 8 + 4];
    // ---- write staged regs (tile t) into LDS buf[cur]
#pragma unroll
    for (int u = 0; u < 4; ++u)
      *(short8*)&Ks[cur][kr_][kc_ + u * 8] = krg[u];
#pragma unroll
    for (int u = 0; u < 4; ++u)
      *(short8*)&VTs[cur][vr_][vc_ + u * 8] = vrg[u];
    __syncthreads();
    // ---- issue K/V loads for tile t+1 (fly under the MFMA phase)
    if (t + 1 < SEQ / 64) {
      const unsigned short* kp = kbase + (size_t)(kt + 64) * ATT;
      const unsigned short* vp = vbase + (kt + 64);
#pragma unroll
      for (int u = 0; u < 4; ++u) krg[u] = *(const short8*)&kp[u * 8];
#pragma unroll
      for (int u = 0; u < 4; ++u) vrg[u] = *(const short8*)&vp[u * 8];
    }
    // ---- QK^T
    f32x4 sc[4];
#pragma unroll
    for (int i = 0; i < 4; ++i) sc[i] = (f32x4)0.f;
#pragma unroll
    for (int nt = 0; nt < 4; ++nt) {
#pragma unroll
      for (int ks = 0; ks < 4; ++ks) {
        short8 bF = *(const short8*)&Ks[cur][nt * 16 + l16][ks * 32 + quad * 8];
        sc[nt] = __builtin_amdgcn_mfma_f32_16x16x32_bf16(aF[ks], bF, sc[nt], 0, 0, 0);
      }
    }
    // ---- p = exp(s); accumulate partial l per lane (no shuffles)
#pragma unroll
    for (int nt = 0; nt < 4; ++nt) {
#pragma unroll
      for (int reg = 0; reg < 4; ++reg) {
        float p = __expf(sc[nt][reg]);
        l_r[reg] += p;
        Ps[wb + quad * 4 + reg][nt * 16 + l16] = f2bf(p);
      }
    }
    // ---- PV + bias@V sharing V fragments
#pragma unroll
    for (int ks = 0; ks < 2; ++ks) {
      short8 pF = *(const short8*)&Ps[wb + l16][ks * 32 + quad * 8];
      short8 bB;
      {
        const float4 u0 = abv[ks * 2], u1 = abv[ks * 2 + 1];
        bB[0] = (short)f2bf(u0.x); bB[1] = (short)f2bf(u0.y);
        bB[2] = (short)f2bf(u0.z); bB[3] = (short)f2bf(u0.w);
        bB[4] = (short)f2bf(u1.x); bB[5] = (short)f2bf(u1.y);
        bB[6] = (short)f2bf(u1.z); bB[7] = (short)f2bf(u1.w);
      }
#pragma unroll
      for (int at = 0; at < 8; ++at) {
        short8 vF = *(const short8*)&VTs[cur][at * 16 + l16][ks * 32 + quad * 8];
        o[at]  = __builtin_amdgcn_mfma_f32_16x16x32_bf16(pF, vF, o[at], 0, 0, 0);
        o2[at] = __builtin_amdgcn_mfma_f32_16x16x32_bf16(bB, vF, o2[at], 0, 0, 0);
      }
    }
  }
  // final l reduction across the 16 l16-lanes, then epilogue
  float inv_l[4];
#pragma unroll
  for (int reg = 0; reg < 4; ++reg) {
    float l = l_r[reg];
    l += __shfl_xor(l, 1, 64);
    l += __shfl_xor(l, 2, 64);
    l += __shfl_xor(l, 4, 64);
    l += __shfl_xor(l, 8, 64);
    inv_l[reg] = 1.0f / l;
  }
#pragma unroll
  for (int at = 0; at < 8; ++at) {
    const int col = vi * ATT + at * 16 + l16;
#pragma unroll
    for (int reg = 0; reg < 4; ++reg) {
      const int row = q0 + wb + quad * 4 + reg;
      xbf[(size_t)row * HID + col] = f2bf(o[at][reg] * inv_l[reg] + o2[at][reg]);
    }
  }
}

// ---------------------------------------------------------------------------
// Out projection: out[2048][1024] = xbf[2048][1024](bf16) @ wo + bo  (fp32)
// grid (32, 8), m-tile 64, n-tile 128, K=1024.  Min-2-phase pipelined.
// ---------------------------------------------------------------------------
__global__ __launch_bounds__(256)
void outproj_gemm(const unsigned short* __restrict__ A,
                  const unsigned short* __restrict__ B,  // woT [n][k]
                  const float* __restrict__ bias, float* __restrict__ out) {
  __shared__ alignas(16) unsigned short As[2][64][72];
  __shared__ alignas(16) unsigned short Bs[2][128][72];
  const int tid = threadIdx.x;
  const int m0 = blockIdx.x * 64;
  const int n0 = blockIdx.y * 128;
  const int w = tid >> 6, lane = tid & 63;
  const int l16 = lane & 15, quad = lane >> 4;
  const int ar = tid >> 2, ac = (tid & 3) * 16;
  const int br = tid >> 1, bc = (tid & 1) * 32;
  const unsigned short* abase = &A[(size_t)(m0 + ar) * HID + ac];
  const unsigned short* bbase = &B[(size_t)(n0 + br) * HID + bc];

  f32x4 acc[8];
#pragma unroll
  for (int i = 0; i < 8; ++i) acc[i] = (f32x4)0.f;

  // prologue: issue loads for k-tile 0
  short8 arg0, arg1, brg[4];
  arg0 = *(const short8*)&abase[0];
  arg1 = *(const short8*)&abase[8];
#pragma unroll
  for (int u = 0; u < 4; ++u) brg[u] = *(const short8*)&bbase[u * 8];

  for (int kk = 0; kk < HID / 64; ++kk) {
    const int cur = kk & 1;
    // write staged regs into LDS buf[cur]
    *(short8*)&As[cur][ar][ac]     = arg0;
    *(short8*)&As[cur][ar][ac + 8] = arg1;
#pragma unroll
    for (int u = 0; u < 4; ++u)
      *(short8*)&Bs[cur][br][bc + u * 8] = brg[u];
    __syncthreads();
    // issue loads for k-tile kk+1
    if (kk + 1 < HID / 64) {
      const unsigned short* ap = abase + (kk + 1) * 64;
      const unsigned short* bp = bbase + (kk + 1) * 64;
      arg0 = *(const short8*)&ap[0];
      arg1 = *(const short8*)&ap[8];
#pragma unroll
      for (int u = 0; u < 4; ++u) brg[u] = *(const short8*)&bp[u * 8];
    }
    // compute from buf[cur]
#pragma unroll
    for (int ks = 0; ks < 2; ++ks) {
      short8 af = *(const short8*)&As[cur][w * 16 + l16][ks * 32 + quad * 8];
#pragma unroll
      for (int nt = 0; nt < 8; ++nt) {
        short8 bf = *(const short8*)&Bs[cur][nt * 16 + l16][ks * 32 + quad * 8];
        acc[nt] = __builtin_amdgcn_mfma_f32_16x16x32_bf16(af, bf, acc[nt], 0, 0, 0);
      }
    }
  }
#pragma unroll
  for (int nt = 0; nt < 8; ++nt) {
    const int col = n0 + nt * 16 + l16;
    const float bvv = bias[col];
#pragma unroll
    for (int reg = 0; reg < 4; ++reg) {
      const int row = m0 + w * 16 + quad * 4 + reg;
      out[(size_t)row * HID + col] = acc[nt][reg] + bvv;
    }
  }
}

// ---------------------------------------------------------------------------
extern "C" void kernel_launch(void* const* d_in, const int* in_sizes, int n_in,
                              void* d_out, int out_size, void* d_ws, size_t ws_size,
                              hipStream_t stream) {
  const float* q   = (const float*)d_in[0];
  const float* k   = (const float*)d_in[1];
  const float* v   = (const float*)d_in[2];
  const float* ab  = (const float*)d_in[3];
  const float* wq  = (const float*)d_in[4];
  const float* bq  = (const float*)d_in[5];
  const float* wk  = (const float*)d_in[6];
  const float* bk  = (const float*)d_in[7];
  const float* wv  = (const float*)d_in[8];
  const float* bv  = (const float*)d_in[9];
  const float* wo  = (const float*)d_in[10];
  const float* bo  = (const float*)d_in[11];
  float* out = (float*)d_out;

  char* ws = (char*)d_ws;
  const size_t PROJ_B = (size_t)VIEWS * SEQ * ATT * 2;  // 4 MB bf16
  unsigned short* qh  = (unsigned short*)(ws);
  unsigned short* kh  = (unsigned short*)(ws + PROJ_B);
  unsigned short* vhT = (unsigned short*)(ws + 2 * PROJ_B);
  unsigned short* xbf = (unsigned short*)(ws + 3 * PROJ_B);
  char* wbase = ws + 4 * PROJ_B;
  unsigned short* wqT = (unsigned short*)(wbase);
  unsigned short* wkT = (unsigned short*)(wbase + 262144);
  unsigned short* wvT = (unsigned short*)(wbase + 2 * 262144);
  unsigned short* woT = (unsigned short*)(wbase + 3 * 262144);

  dim3 blk(256);
  transpose_qkvw<<<dim3(2, 16, 3), blk, 0, stream>>>(wq, wk, wv, wqT, wkT, wvT);
  transpose_cvt_f32_bf16<<<dim3(16, 16), blk, 0, stream>>>(wo, woT, HID, HID);
  qkv_proj<<<dim3(512, 1, 3), blk, 0, stream>>>(q, k, v, wqT, wkT, wvT,
                                                bq, bk, bv, qh, kh, vhT);
  flash_fused<<<dim3(VIEWS, SEQ / 64), blk, 0, stream>>>(qh, kh, vhT, ab, xbf);
  outproj_gemm<<<dim3(SEQ / 64, HID / 128), blk, 0, stream>>>(xbf, woT, bo, out);
}

// Round 4
// 430.245 us; speedup vs baseline: 1.1295x; 1.1295x over previous
//
#include <hip/hip_runtime.h>
#include <math.h>

#define VIEWS 8
#define SEQ 2048
#define HID 1024
#define ATT 128
#define QSCALE 0.08838834764831845f  // 128^-0.5

typedef __attribute__((ext_vector_type(8))) short short8;
typedef __attribute__((ext_vector_type(4))) float f32x4;

__device__ __forceinline__ unsigned short f2bf(float f) {
  union { float f; unsigned u; } a; a.f = f;
  unsigned r = a.u + 0x7FFF + ((a.u >> 16) & 1);  // RNE
  return (unsigned short)(r >> 16);
}

// ---------------------------------------------------------------------------
// Transpose + convert fp32 [R][C] -> bf16 [C][R].  R,C multiples of 64.
// ---------------------------------------------------------------------------
__global__ __launch_bounds__(256)
void transpose_cvt_f32_bf16(const float* __restrict__ in,
                            unsigned short* __restrict__ out, int R, int C) {
  __shared__ alignas(16) unsigned short T[64][72];
  const int tid = threadIdx.x;
  const int r0 = blockIdx.y * 64, c0 = blockIdx.x * 64;
  const int tr = tid >> 2, tc = (tid & 3) * 16;
#pragma unroll
  for (int u = 0; u < 4; ++u) {
    float4 t = *(const float4*)&in[(size_t)(r0 + tr) * C + c0 + tc + u * 4];
    T[tc + u * 4 + 0][tr] = f2bf(t.x);
    T[tc + u * 4 + 1][tr] = f2bf(t.y);
    T[tc + u * 4 + 2][tr] = f2bf(t.z);
    T[tc + u * 4 + 3][tr] = f2bf(t.w);
  }
  __syncthreads();
  const int oc = tid >> 2, orr = (tid & 3) * 16;
#pragma unroll
  for (int u = 0; u < 2; ++u)
    *(short8*)&out[(size_t)(c0 + oc) * R + r0 + orr + u * 8] =
        *(const short8*)&T[oc][orr + u * 8];
}

// Batched variant for wq/wk/wv (z selects). R=1024, C=128. grid (2,16,3).
__global__ __launch_bounds__(256)
void transpose_qkvw(const float* __restrict__ wq, const float* __restrict__ wk,
                    const float* __restrict__ wv, unsigned short* __restrict__ oq,
                    unsigned short* __restrict__ ok, unsigned short* __restrict__ ov) {
  __shared__ alignas(16) unsigned short T[64][72];
  const int z = blockIdx.z;
  const float* in = (z == 0) ? wq : (z == 1) ? wk : wv;
  unsigned short* out = (z == 0) ? oq : (z == 1) ? ok : ov;
  const int R = HID, C = ATT;
  const int tid = threadIdx.x;
  const int r0 = blockIdx.y * 64, c0 = blockIdx.x * 64;
  const int tr = tid >> 2, tc = (tid & 3) * 16;
#pragma unroll
  for (int u = 0; u < 4; ++u) {
    float4 t = *(const float4*)&in[(size_t)(r0 + tr) * C + c0 + tc + u * 4];
    T[tc + u * 4 + 0][tr] = f2bf(t.x);
    T[tc + u * 4 + 1][tr] = f2bf(t.y);
    T[tc + u * 4 + 2][tr] = f2bf(t.z);
    T[tc + u * 4 + 3][tr] = f2bf(t.w);
  }
  __syncthreads();
  const int oc = tid >> 2, orr = (tid & 3) * 16;
#pragma unroll
  for (int u = 0; u < 2; ++u)
    *(short8*)&out[(size_t)(c0 + oc) * R + r0 + orr + u * 8] =
        *(const short8*)&T[oc][orr + u * 8];
}

// ---------------------------------------------------------------------------
// Fused QKV projection, hybrid staging:
//   A (fp32 activations): reg-staged prefetch -> f2bf -> LDS (double-buffer,
//     ONE barrier per K-iter; next tile's loads fly under the MFMA phase).
//   B (bf16 weights, pre-transposed wT[n][k]): direct-from-global fragments
//     in MFMA layout — L2-resident, line-coalesced, no barrier dependency.
// m-tile 32 (waves: 2m x 2n), grid (512,1,3) => 6 blocks/CU for latency hiding.
// ---------------------------------------------------------------------------
__global__ __launch_bounds__(256, 4)
void qkv_proj(const float* __restrict__ q, const float* __restrict__ k,
              const float* __restrict__ v, const unsigned short* __restrict__ wqT,
              const unsigned short* __restrict__ wkT,
              const unsigned short* __restrict__ wvT,
              const float* __restrict__ bq, const float* __restrict__ bk,
              const float* __restrict__ bv, unsigned short* __restrict__ qh,
              unsigned short* __restrict__ kh, unsigned short* __restrict__ vhT) {
  __shared__ alignas(16) unsigned short As[2][32][72];
  const int z = blockIdx.z;
  const float* A = (z == 0) ? q : (z == 1) ? k : v;
  const unsigned short* B = (z == 0) ? wqT : (z == 1) ? wkT : wvT;
  const float* bias = (z == 0) ? bq : (z == 1) ? bk : bv;
  const float scale = (z == 0) ? QSCALE : 1.0f;
  const int tid = threadIdx.x;
  const int w = tid >> 6, lane = tid & 63;
  const int l16 = lane & 15, quad = lane >> 4;
  const int m0 = blockIdx.x * 32;
  const int wm = (w & 1) * 16;      // wave's 16-row slab within the 32-row tile
  const int n0 = (w >> 1) * 64;     // wave's 64-col half of ATT=128

  // A staging: thread covers 8 consecutive fp32 of one row (32 rows x 64 cols)
  const int ar = tid >> 3, ac = (tid & 7) * 8;
  const float* abase = &A[(size_t)(m0 + ar) * HID + ac];
  // B fragment base: row n0+l16, k-offset quad*8 (lane-coalesced to 64B lines)
  const unsigned short* bbase = &B[(size_t)(n0 + l16) * HID + quad * 8];

  f32x4 acc[4];
#pragma unroll
  for (int i = 0; i < 4; ++i) acc[i] = (f32x4)0.f;

  // prologue: stage k-tile 0 A into regs
  float4 ag0 = *(const float4*)&abase[0];
  float4 ag1 = *(const float4*)&abase[4];

  for (int kk = 0; kk < HID / 64; ++kk) {
    const int cur = kk & 1;
    const int k0 = kk * 64;
    // convert staged fp32 -> bf16, write to LDS buf[cur]
    {
      short8 st;
      st[0] = (short)f2bf(ag0.x); st[1] = (short)f2bf(ag0.y);
      st[2] = (short)f2bf(ag0.z); st[3] = (short)f2bf(ag0.w);
      st[4] = (short)f2bf(ag1.x); st[5] = (short)f2bf(ag1.y);
      st[6] = (short)f2bf(ag1.z); st[7] = (short)f2bf(ag1.w);
      *(short8*)&As[cur][ar][ac] = st;
    }
    __syncthreads();
    // prefetch next A k-tile (flies under B-loads + MFMA below)
    if (kk + 1 < HID / 64) {
      ag0 = *(const float4*)&abase[k0 + 64];
      ag1 = *(const float4*)&abase[k0 + 68];
    }
    // B fragments for this k-tile: nt in 0..3, ks in 0..1 (8 x 16B, L2-hot)
    short8 bfr[8];
#pragma unroll
    for (int nt = 0; nt < 4; ++nt) {
      bfr[nt * 2]     = *(const short8*)&bbase[(size_t)nt * 16 * HID + k0];
      bfr[nt * 2 + 1] = *(const short8*)&bbase[(size_t)nt * 16 * HID + k0 + 32];
    }
    // A fragments from LDS
    short8 af0 = *(const short8*)&As[cur][wm + l16][quad * 8];
    short8 af1 = *(const short8*)&As[cur][wm + l16][32 + quad * 8];
#pragma unroll
    for (int nt = 0; nt < 4; ++nt) {
      acc[nt] = __builtin_amdgcn_mfma_f32_16x16x32_bf16(af0, bfr[nt * 2],     acc[nt], 0, 0, 0);
      acc[nt] = __builtin_amdgcn_mfma_f32_16x16x32_bf16(af1, bfr[nt * 2 + 1], acc[nt], 0, 0, 0);
    }
  }

  if (z < 2) {
    unsigned short* outp = (z == 0) ? qh : kh;
#pragma unroll
    for (int nt = 0; nt < 4; ++nt) {
      const int col = n0 + nt * 16 + l16;
      const float bvv = bias[col];
#pragma unroll
      for (int reg = 0; reg < 4; ++reg) {
        const int row = m0 + wm + quad * 4 + reg;
        outp[(size_t)row * ATT + col] = f2bf((acc[nt][reg] + bvv) * scale);
      }
    }
  } else {
    // transposed store: vhT[vi][a][s]; 4 consecutive rows share vi (32 | 2048)
    const int gr = m0 + wm + quad * 4;
    const int vi = gr >> 11, s = gr & (SEQ - 1);
#pragma unroll
    for (int nt = 0; nt < 4; ++nt) {
      const int col = n0 + nt * 16 + l16;
      const float bvv = bias[col];
      ushort4 pk;
      pk.x = f2bf(acc[nt][0] + bvv);
      pk.y = f2bf(acc[nt][1] + bvv);
      pk.z = f2bf(acc[nt][2] + bvv);
      pk.w = f2bf(acc[nt][3] + bvv);
      *(ushort4*)&vhT[((size_t)vi * ATT + col) * SEQ + s] = pk;
    }
  }
}

// ---------------------------------------------------------------------------
// Fused flash attention + post-softmax-bias@V, min-2-phase pipelined:
//   per iter: ds_write tile t (from regs) -> barrier -> issue loads t+1 ->
//   compute tile t.  Loads for t+1 fly under the MFMA phase (T14/T3-min).
// grid (VIEWS, SEQ/64); LDS = 96 KB -> 1 block/CU.
// ---------------------------------------------------------------------------
__global__ __launch_bounds__(256, 1)
void flash_fused(const unsigned short* __restrict__ qh,
                 const unsigned short* __restrict__ kh,
                 const unsigned short* __restrict__ vhT,
                 const float* __restrict__ ab,
                 unsigned short* __restrict__ xbf) {
  __shared__ alignas(16) unsigned short Qs[64][136];
  __shared__ alignas(16) unsigned short Ks[2][64][136];
  __shared__ alignas(16) unsigned short VTs[2][128][72];
  __shared__ alignas(16) unsigned short Ps[64][72];
  const int tid = threadIdx.x;
  const int vi = blockIdx.x;
  const int q0 = blockIdx.y * 64;
  const int w = tid >> 6, lane = tid & 63;
  const int l16 = lane & 15, quad = lane >> 4;
  const int wb = w * 16;

  // staging coordinates
  const int kr_ = tid >> 2, kc_ = (tid & 3) * 32;   // K tile [64 keys][128]
  const int vr_ = tid >> 1, vc_ = (tid & 1) * 32;   // V^T tile [128 a][64 keys]
  const unsigned short* kbase = &kh[((size_t)vi * SEQ + kr_) * ATT + kc_];
  const unsigned short* vbase = &vhT[((size_t)vi * ATT + vr_) * SEQ + vc_];

  {  // stage Q tile once
    const int r = tid >> 2, c = (tid & 3) * 32;
    const unsigned short* src = &qh[((size_t)vi * SEQ + q0 + r) * ATT + c];
#pragma unroll
    for (int u = 0; u < 4; ++u)
      *(short8*)&Qs[r][c + u * 8] = *(const short8*)&src[u * 8];
  }

  // prologue: issue K/V loads for tile 0 into regs
  short8 krg[4], vrg[4];
#pragma unroll
  for (int u = 0; u < 4; ++u) krg[u] = *(const short8*)&kbase[u * 8];
#pragma unroll
  for (int u = 0; u < 4; ++u) vrg[u] = *(const short8*)&vbase[u * 8];

  __syncthreads();  // Qs visible
  short8 aF[4];
#pragma unroll
  for (int ks = 0; ks < 4; ++ks)
    aF[ks] = *(const short8*)&Qs[wb + l16][ks * 32 + quad * 8];

  float l_r[4] = {0.f, 0.f, 0.f, 0.f};
  f32x4 o[8], o2[8];
#pragma unroll
  for (int i = 0; i < 8; ++i) { o[i] = (f32x4)0.f; o2[i] = (f32x4)0.f; }

  const float* abrow = &ab[((size_t)vi * SEQ + q0 + wb + l16) * SEQ];

  for (int t = 0; t < SEQ / 64; ++t) {
    const int kt = t * 64;
    const int cur = t & 1;
    // bias fragment loads for tile t (issued early, consumed in PV phase)
    float4 abv[4];
    abv[0] = *(const float4*)&abrow[kt + quad * 8];
    abv[1] = *(const float4*)&abrow[kt + quad * 8 + 4];
    abv[2] = *(const float4*)&abrow[kt + 32 + quad * 8];
    abv[3] = *(const float4*)&abrow[kt + 32 + quad * 8 + 4];
    // ---- write staged regs (tile t) into LDS buf[cur]
#pragma unroll
    for (int u = 0; u < 4; ++u)
      *(short8*)&Ks[cur][kr_][kc_ + u * 8] = krg[u];
#pragma unroll
    for (int u = 0; u < 4; ++u)
      *(short8*)&VTs[cur][vr_][vc_ + u * 8] = vrg[u];
    __syncthreads();
    // ---- issue K/V loads for tile t+1 (fly under the MFMA phase)
    if (t + 1 < SEQ / 64) {
      const unsigned short* kp = kbase + (size_t)(kt + 64) * ATT;
      const unsigned short* vp = vbase + (kt + 64);
#pragma unroll
      for (int u = 0; u < 4; ++u) krg[u] = *(const short8*)&kp[u * 8];
#pragma unroll
      for (int u = 0; u < 4; ++u) vrg[u] = *(const short8*)&vp[u * 8];
    }
    // ---- QK^T
    f32x4 sc[4];
#pragma unroll
    for (int i = 0; i < 4; ++i) sc[i] = (f32x4)0.f;
#pragma unroll
    for (int nt = 0; nt < 4; ++nt) {
#pragma unroll
      for (int ks = 0; ks < 4; ++ks) {
        short8 bF = *(const short8*)&Ks[cur][nt * 16 + l16][ks * 32 + quad * 8];
        sc[nt] = __builtin_amdgcn_mfma_f32_16x16x32_bf16(aF[ks], bF, sc[nt], 0, 0, 0);
      }
    }
    // ---- p = exp(s); accumulate partial l per lane (no shuffles)
#pragma unroll
    for (int nt = 0; nt < 4; ++nt) {
#pragma unroll
      for (int reg = 0; reg < 4; ++reg) {
        float p = __expf(sc[nt][reg]);
        l_r[reg] += p;
        Ps[wb + quad * 4 + reg][nt * 16 + l16] = f2bf(p);
      }
    }
    // ---- PV + bias@V sharing V fragments
#pragma unroll
    for (int ks = 0; ks < 2; ++ks) {
      short8 pF = *(const short8*)&Ps[wb + l16][ks * 32 + quad * 8];
      short8 bB;
      {
        const float4 u0 = abv[ks * 2], u1 = abv[ks * 2 + 1];
        bB[0] = (short)f2bf(u0.x); bB[1] = (short)f2bf(u0.y);
        bB[2] = (short)f2bf(u0.z); bB[3] = (short)f2bf(u0.w);
        bB[4] = (short)f2bf(u1.x); bB[5] = (short)f2bf(u1.y);
        bB[6] = (short)f2bf(u1.z); bB[7] = (short)f2bf(u1.w);
      }
#pragma unroll
      for (int at = 0; at < 8; ++at) {
        short8 vF = *(const short8*)&VTs[cur][at * 16 + l16][ks * 32 + quad * 8];
        o[at]  = __builtin_amdgcn_mfma_f32_16x16x32_bf16(pF, vF, o[at], 0, 0, 0);
        o2[at] = __builtin_amdgcn_mfma_f32_16x16x32_bf16(bB, vF, o2[at], 0, 0, 0);
      }
    }
  }
  // final l reduction across the 16 l16-lanes, then epilogue
  float inv_l[4];
#pragma unroll
  for (int reg = 0; reg < 4; ++reg) {
    float l = l_r[reg];
    l += __shfl_xor(l, 1, 64);
    l += __shfl_xor(l, 2, 64);
    l += __shfl_xor(l, 4, 64);
    l += __shfl_xor(l, 8, 64);
    inv_l[reg] = 1.0f / l;
  }
#pragma unroll
  for (int at = 0; at < 8; ++at) {
    const int col = vi * ATT + at * 16 + l16;
#pragma unroll
    for (int reg = 0; reg < 4; ++reg) {
      const int row = q0 + wb + quad * 4 + reg;
      xbf[(size_t)row * HID + col] = f2bf(o[at][reg] * inv_l[reg] + o2[at][reg]);
    }
  }
}

// ---------------------------------------------------------------------------
// Out projection: out[2048][1024] = xbf[2048][1024](bf16) @ wo + bo  (fp32)
// grid (32, 8), m-tile 64, n-tile 128, K=1024.  Min-2-phase pipelined.
// ---------------------------------------------------------------------------
__global__ __launch_bounds__(256)
void outproj_gemm(const unsigned short* __restrict__ A,
                  const unsigned short* __restrict__ B,  // woT [n][k]
                  const float* __restrict__ bias, float* __restrict__ out) {
  __shared__ alignas(16) unsigned short As[2][64][72];
  __shared__ alignas(16) unsigned short Bs[2][128][72];
  const int tid = threadIdx.x;
  const int m0 = blockIdx.x * 64;
  const int n0 = blockIdx.y * 128;
  const int w = tid >> 6, lane = tid & 63;
  const int l16 = lane & 15, quad = lane >> 4;
  const int ar = tid >> 2, ac = (tid & 3) * 16;
  const int br = tid >> 1, bc = (tid & 1) * 32;
  const unsigned short* abase = &A[(size_t)(m0 + ar) * HID + ac];
  const unsigned short* bbase = &B[(size_t)(n0 + br) * HID + bc];

  f32x4 acc[8];
#pragma unroll
  for (int i = 0; i < 8; ++i) acc[i] = (f32x4)0.f;

  // prologue: issue loads for k-tile 0
  short8 arg0, arg1, brg[4];
  arg0 = *(const short8*)&abase[0];
  arg1 = *(const short8*)&abase[8];
#pragma unroll
  for (int u = 0; u < 4; ++u) brg[u] = *(const short8*)&bbase[u * 8];

  for (int kk = 0; kk < HID / 64; ++kk) {
    const int cur = kk & 1;
    // write staged regs into LDS buf[cur]
    *(short8*)&As[cur][ar][ac]     = arg0;
    *(short8*)&As[cur][ar][ac + 8] = arg1;
#pragma unroll
    for (int u = 0; u < 4; ++u)
      *(short8*)&Bs[cur][br][bc + u * 8] = brg[u];
    __syncthreads();
    // issue loads for k-tile kk+1
    if (kk + 1 < HID / 64) {
      const unsigned short* ap = abase + (kk + 1) * 64;
      const unsigned short* bp = bbase + (kk + 1) * 64;
      arg0 = *(const short8*)&ap[0];
      arg1 = *(const short8*)&ap[8];
#pragma unroll
      for (int u = 0; u < 4; ++u) brg[u] = *(const short8*)&bp[u * 8];
    }
    // compute from buf[cur]
#pragma unroll
    for (int ks = 0; ks < 2; ++ks) {
      short8 af = *(const short8*)&As[cur][w * 16 + l16][ks * 32 + quad * 8];
#pragma unroll
      for (int nt = 0; nt < 8; ++nt) {
        short8 bf = *(const short8*)&Bs[cur][nt * 16 + l16][ks * 32 + quad * 8];
        acc[nt] = __builtin_amdgcn_mfma_f32_16x16x32_bf16(af, bf, acc[nt], 0, 0, 0);
      }
    }
  }
#pragma unroll
  for (int nt = 0; nt < 8; ++nt) {
    const int col = n0 + nt * 16 + l16;
    const float bvv = bias[col];
#pragma unroll
    for (int reg = 0; reg < 4; ++reg) {
      const int row = m0 + w * 16 + quad * 4 + reg;
      out[(size_t)row * HID + col] = acc[nt][reg] + bvv;
    }
  }
}

// ---------------------------------------------------------------------------
extern "C" void kernel_launch(void* const* d_in, const int* in_sizes, int n_in,
                              void* d_out, int out_size, void* d_ws, size_t ws_size,
                              hipStream_t stream) {
  const float* q   = (const float*)d_in[0];
  const float* k   = (const float*)d_in[1];
  const float* v   = (const float*)d_in[2];
  const float* ab  = (const float*)d_in[3];
  const float* wq  = (const float*)d_in[4];
  const float* bq  = (const float*)d_in[5];
  const float* wk  = (const float*)d_in[6];
  const float* bk  = (const float*)d_in[7];
  const float* wv  = (const float*)d_in[8];
  const float* bv  = (const float*)d_in[9];
  const float* wo  = (const float*)d_in[10];
  const float* bo  = (const float*)d_in[11];
  float* out = (float*)d_out;

  char* ws = (char*)d_ws;
  const size_t PROJ_B = (size_t)VIEWS * SEQ * ATT * 2;  // 4 MB bf16
  unsigned short* qh  = (unsigned short*)(ws);
  unsigned short* kh  = (unsigned short*)(ws + PROJ_B);
  unsigned short* vhT = (unsigned short*)(ws + 2 * PROJ_B);
  unsigned short* xbf = (unsigned short*)(ws + 3 * PROJ_B);
  char* wbase = ws + 4 * PROJ_B;
  unsigned short* wqT = (unsigned short*)(wbase);
  unsigned short* wkT = (unsigned short*)(wbase + 262144);
  unsigned short* wvT = (unsigned short*)(wbase + 2 * 262144);
  unsigned short* woT = (unsigned short*)(wbase + 3 * 262144);

  dim3 blk(256);
  transpose_qkvw<<<dim3(2, 16, 3), blk, 0, stream>>>(wq, wk, wv, wqT, wkT, wvT);
  transpose_cvt_f32_bf16<<<dim3(16, 16), blk, 0, stream>>>(wo, woT, HID, HID);
  qkv_proj<<<dim3(512, 1, 3), blk, 0, stream>>>(q, k, v, wqT, wkT, wvT,
                                                bq, bk, bv, qh, kh, vhT);
  flash_fused<<<dim3(VIEWS, SEQ / 64), blk, 0, stream>>>(qh, kh, vhT, ab, xbf);
  outproj_gemm<<<dim3(SEQ / 64, HID / 128), blk, 0, stream>>>(xbf, woT, bo, out);
}

// Round 5
// 427.651 us; speedup vs baseline: 1.1364x; 1.0061x over previous
//
#include <hip/hip_runtime.h>
#include <math.h>

#define VIEWS 8
#define SEQ 2048
#define HID 1024
#define ATT 128
#define QSCALE 0.08838834764831845f  // 128^-0.5

typedef __attribute__((ext_vector_type(8))) short short8;
typedef __attribute__((ext_vector_type(4))) float f32x4;

#define GLOAD_LDS16(g, l)                                                     \
  __builtin_amdgcn_global_load_lds(                                           \
      (const __attribute__((address_space(1))) unsigned int*)(g),             \
      (__attribute__((address_space(3))) unsigned int*)(l), 16, 0, 0)

__device__ __forceinline__ unsigned short f2bf(float f) {
  union { float f; unsigned u; } a; a.f = f;
  unsigned r = a.u + 0x7FFF + ((a.u >> 16) & 1);  // RNE
  return (unsigned short)(r >> 16);
}

// ---------------------------------------------------------------------------
// Transpose + convert fp32 [R][C] -> bf16 [C][R].  R,C multiples of 64.
// ---------------------------------------------------------------------------
__global__ __launch_bounds__(256)
void transpose_cvt_f32_bf16(const float* __restrict__ in,
                            unsigned short* __restrict__ out, int R, int C) {
  __shared__ alignas(16) unsigned short T[64][72];
  const int tid = threadIdx.x;
  const int r0 = blockIdx.y * 64, c0 = blockIdx.x * 64;
  const int tr = tid >> 2, tc = (tid & 3) * 16;
#pragma unroll
  for (int u = 0; u < 4; ++u) {
    float4 t = *(const float4*)&in[(size_t)(r0 + tr) * C + c0 + tc + u * 4];
    T[tc + u * 4 + 0][tr] = f2bf(t.x);
    T[tc + u * 4 + 1][tr] = f2bf(t.y);
    T[tc + u * 4 + 2][tr] = f2bf(t.z);
    T[tc + u * 4 + 3][tr] = f2bf(t.w);
  }
  __syncthreads();
  const int oc = tid >> 2, orr = (tid & 3) * 16;
#pragma unroll
  for (int u = 0; u < 2; ++u)
    *(short8*)&out[(size_t)(c0 + oc) * R + r0 + orr + u * 8] =
        *(const short8*)&T[oc][orr + u * 8];
}

// Batched variant for wq/wk/wv (z selects). R=1024, C=128. grid (2,16,3).
__global__ __launch_bounds__(256)
void transpose_qkvw(const float* __restrict__ wq, const float* __restrict__ wk,
                    const float* __restrict__ wv, unsigned short* __restrict__ oq,
                    unsigned short* __restrict__ ok, unsigned short* __restrict__ ov) {
  __shared__ alignas(16) unsigned short T[64][72];
  const int z = blockIdx.z;
  const float* in = (z == 0) ? wq : (z == 1) ? wk : wv;
  unsigned short* out = (z == 0) ? oq : (z == 1) ? ok : ov;
  const int R = HID, C = ATT;
  const int tid = threadIdx.x;
  const int r0 = blockIdx.y * 64, c0 = blockIdx.x * 64;
  const int tr = tid >> 2, tc = (tid & 3) * 16;
#pragma unroll
  for (int u = 0; u < 4; ++u) {
    float4 t = *(const float4*)&in[(size_t)(r0 + tr) * C + c0 + tc + u * 4];
    T[tc + u * 4 + 0][tr] = f2bf(t.x);
    T[tc + u * 4 + 1][tr] = f2bf(t.y);
    T[tc + u * 4 + 2][tr] = f2bf(t.z);
    T[tc + u * 4 + 3][tr] = f2bf(t.w);
  }
  __syncthreads();
  const int oc = tid >> 2, orr = (tid & 3) * 16;
#pragma unroll
  for (int u = 0; u < 2; ++u)
    *(short8*)&out[(size_t)(c0 + oc) * R + r0 + orr + u * 8] =
        *(const short8*)&T[oc][orr + u * 8];
}

// ---------------------------------------------------------------------------
// Fused QKV projection — m97-style global_load_lds staging (no VGPR round
// trip => the DMA queue, not the register allocator, holds in-flight state).
//   A: fp32 [32][64] linear LDS; convert fp32->bf16 at fragment build.
//   B: bf16 [128][64] linear LDS (pre-transposed wT[n][k]).
// One barrier per K-step; STAGE(t+1) issued right after it, drained by the
// next barrier (overlapped with compute).  m-tile 32, 4 waves = 2m x 2n.
// LDS 48 KB -> 3 blocks/CU; grid (512,1,3).
// ---------------------------------------------------------------------------
__global__ __launch_bounds__(256, 2)
void qkv_proj(const float* __restrict__ q, const float* __restrict__ k,
              const float* __restrict__ v, const unsigned short* __restrict__ wqT,
              const unsigned short* __restrict__ wkT,
              const unsigned short* __restrict__ wvT,
              const float* __restrict__ bq, const float* __restrict__ bk,
              const float* __restrict__ bv, unsigned short* __restrict__ qh,
              unsigned short* __restrict__ kh, unsigned short* __restrict__ vhT) {
  __shared__ alignas(16) float Af[2][32][64];
  __shared__ alignas(16) unsigned short Bf[2][128][64];
  const int z = blockIdx.z;
  const float* A = (z == 0) ? q : (z == 1) ? k : v;
  const unsigned short* B = (z == 0) ? wqT : (z == 1) ? wkT : wvT;
  const float* bias = (z == 0) ? bq : (z == 1) ? bk : bv;
  const float scale = (z == 0) ? QSCALE : 1.0f;
  const int tid = threadIdx.x;
  const int w = tid >> 6, lane = tid & 63;
  const int l16 = lane & 15, quad = lane >> 4;
  const int m0 = blockIdx.x * 32;
  const int wm = (w & 1) * 16;     // wave's 16-row q-slab
  const int n0 = (w >> 1) * 64;    // wave's 64-col half of ATT

  // per-lane global sources for the wave's DMA chunks (1 KB each)
  // A: chunk c = w*2+j covers rows c*4..c*4+3; lane -> row c*4+(lane>>4),
  //    col (lane&15)*4 fp32 (16 B)
  const float* ag[2];
#pragma unroll
  for (int j = 0; j < 2; ++j)
    ag[j] = &A[(size_t)(m0 + (w * 2 + j) * 4 + (lane >> 4)) * HID + (lane & 15) * 4];
  // B: chunk c = w*4+j covers rows c*8..c*8+7; lane -> row c*8+(lane>>3),
  //    col (lane&7)*8 shorts (16 B)
  const unsigned short* bg[4];
#pragma unroll
  for (int j = 0; j < 4; ++j)
    bg[j] = &B[(size_t)((w * 4 + j) * 8 + (lane >> 3)) * HID + (lane & 7) * 8];

  f32x4 acc[4];
#pragma unroll
  for (int i = 0; i < 4; ++i) acc[i] = (f32x4)0.f;

#define QKV_STAGE(nxt, k0)                                                    \
  do {                                                                        \
    _Pragma("unroll") for (int j = 0; j < 2; ++j)                             \
        GLOAD_LDS16(ag[j] + (k0), &Af[nxt][(w * 2 + j) * 4][0]);              \
    _Pragma("unroll") for (int j = 0; j < 4; ++j)                             \
        GLOAD_LDS16(bg[j] + (k0), &Bf[nxt][(w * 4 + j) * 8][0]);              \
  } while (0)

  QKV_STAGE(0, 0);
  int cur = 0;
  for (int kk = 0; kk < HID / 64; ++kk) {
    __syncthreads();  // drains DMA for buf[cur] (and prev ds_reads)
    if (kk + 1 < HID / 64) QKV_STAGE(cur ^ 1, (kk + 1) * 64);
    // A fragments (fp32 -> bf16 at build)
    const float4 a0 = *(const float4*)&Af[cur][wm + l16][quad * 8];
    const float4 a1 = *(const float4*)&Af[cur][wm + l16][quad * 8 + 4];
    const float4 a2 = *(const float4*)&Af[cur][wm + l16][32 + quad * 8];
    const float4 a3 = *(const float4*)&Af[cur][wm + l16][36 + quad * 8];
    short8 af0, af1;
    af0[0] = (short)f2bf(a0.x); af0[1] = (short)f2bf(a0.y);
    af0[2] = (short)f2bf(a0.z); af0[3] = (short)f2bf(a0.w);
    af0[4] = (short)f2bf(a1.x); af0[5] = (short)f2bf(a1.y);
    af0[6] = (short)f2bf(a1.z); af0[7] = (short)f2bf(a1.w);
    af1[0] = (short)f2bf(a2.x); af1[1] = (short)f2bf(a2.y);
    af1[2] = (short)f2bf(a2.z); af1[3] = (short)f2bf(a2.w);
    af1[4] = (short)f2bf(a3.x); af1[5] = (short)f2bf(a3.y);
    af1[6] = (short)f2bf(a3.z); af1[7] = (short)f2bf(a3.w);
#pragma unroll
    for (int nt = 0; nt < 4; ++nt) {
      const short8 b0 = *(const short8*)&Bf[cur][n0 + nt * 16 + l16][quad * 8];
      const short8 b1 = *(const short8*)&Bf[cur][n0 + nt * 16 + l16][32 + quad * 8];
      acc[nt] = __builtin_amdgcn_mfma_f32_16x16x32_bf16(af0, b0, acc[nt], 0, 0, 0);
      acc[nt] = __builtin_amdgcn_mfma_f32_16x16x32_bf16(af1, b1, acc[nt], 0, 0, 0);
    }
    cur ^= 1;
  }
#undef QKV_STAGE

  if (z < 2) {
    unsigned short* outp = (z == 0) ? qh : kh;
#pragma unroll
    for (int nt = 0; nt < 4; ++nt) {
      const int col = n0 + nt * 16 + l16;
      const float bvv = bias[col];
#pragma unroll
      for (int reg = 0; reg < 4; ++reg) {
        const int row = m0 + wm + quad * 4 + reg;
        outp[(size_t)row * ATT + col] = f2bf((acc[nt][reg] + bvv) * scale);
      }
    }
  } else {
    // transposed store: vhT[vi][a][s]; 4 consecutive rows share vi (32 | 2048)
    const int gr = m0 + wm + quad * 4;
    const int vi = gr >> 11, s = gr & (SEQ - 1);
#pragma unroll
    for (int nt = 0; nt < 4; ++nt) {
      const int col = n0 + nt * 16 + l16;
      const float bvv = bias[col];
      ushort4 pk;
      pk.x = f2bf(acc[nt][0] + bvv);
      pk.y = f2bf(acc[nt][1] + bvv);
      pk.z = f2bf(acc[nt][2] + bvv);
      pk.w = f2bf(acc[nt][3] + bvv);
      *(ushort4*)&vhT[((size_t)vi * ATT + col) * SEQ + s] = pk;
    }
  }
}

// ---------------------------------------------------------------------------
// Fused flash attention + post-softmax-bias@V.  Q-tile 32 for 2 blocks/CU.
// 4 waves: (w&1) selects 16-row q-slab; (w>>1) selects key-half in QK^T and
// a-half in PV.  Ps (and the l-combine buffer Ls) alias the dead Qs region.
// grid (VIEWS, SEQ/32) = (8,64) = 512 blocks; LDS 78.5 KB -> 2 blocks/CU.
// ---------------------------------------------------------------------------
__global__ __launch_bounds__(256, 2)
void flash_fused(const unsigned short* __restrict__ qh,
                 const unsigned short* __restrict__ kh,
                 const unsigned short* __restrict__ vhT,
                 const float* __restrict__ ab,
                 unsigned short* __restrict__ xbf) {
  __shared__ alignas(16) char QPs[32 * 136 * 2];  // Qs[32][136]; later Ps[32][72]+Ls[64]
  __shared__ alignas(16) unsigned short Ks[2][64][136];
  __shared__ alignas(16) unsigned short VTs[2][128][72];
  unsigned short (*Qs)[136] = (unsigned short(*)[136])QPs;
  unsigned short (*Ps)[72]  = (unsigned short(*)[72])QPs;
  float* Ls = (float*)(QPs + 32 * 72 * 2);        // 64 floats, disjoint from Ps
  const int tid = threadIdx.x;
  const int vi = blockIdx.x;
  const int q0 = blockIdx.y * 32;
  const int w = tid >> 6, lane = tid & 63;
  const int l16 = lane & 15, quad = lane >> 4;
  const int wq_ = (w & 1) * 16;  // q-row slab
  const int wh = w >> 1;         // key-half (QK) / a-half (PV)

  // staging coordinates
  const int kr_ = tid >> 2, kc_ = (tid & 3) * 32;  // K tile [64 keys][128]
  const int vr_ = tid >> 1, vc_ = (tid & 1) * 32;  // V^T tile [128 a][64 keys]
  const unsigned short* kbase = &kh[((size_t)vi * SEQ + kr_) * ATT + kc_];
  const unsigned short* vbase = &vhT[((size_t)vi * ATT + vr_) * SEQ + vc_];

  {  // stage Q tile (32 x 128)
    const int r = tid >> 3, c = (tid & 7) * 16;
    const unsigned short* src = &qh[((size_t)vi * SEQ + q0 + r) * ATT + c];
    *(short8*)&Qs[r][c]     = *(const short8*)&src[0];
    *(short8*)&Qs[r][c + 8] = *(const short8*)&src[8];
  }
  // prologue: K/V tile 0 into regs
  short8 krg[4], vrg[4];
#pragma unroll
  for (int u = 0; u < 4; ++u) krg[u] = *(const short8*)&kbase[u * 8];
#pragma unroll
  for (int u = 0; u < 4; ++u) vrg[u] = *(const short8*)&vbase[u * 8];

  __syncthreads();  // Qs visible
  short8 aF[4];
#pragma unroll
  for (int ks = 0; ks < 4; ++ks)
    aF[ks] = *(const short8*)&Qs[wq_ + l16][ks * 32 + quad * 8];
  // (all waves read aF before their first loop barrier, so the Ps alias of
  //  Qs is safe: first Ps write is after BARRIER1 of iter 0)

  float l_r[4] = {0.f, 0.f, 0.f, 0.f};
  f32x4 o[4], o2[4];
#pragma unroll
  for (int i = 0; i < 4; ++i) { o[i] = (f32x4)0.f; o2[i] = (f32x4)0.f; }

  const float* abrow = &ab[((size_t)vi * SEQ + q0 + wq_ + l16) * SEQ];

  for (int t = 0; t < SEQ / 64; ++t) {
    const int kt = t * 64;
    const int cur = t & 1;
    float4 abv[4];
    abv[0] = *(const float4*)&abrow[kt + quad * 8];
    abv[1] = *(const float4*)&abrow[kt + quad * 8 + 4];
    abv[2] = *(const float4*)&abrow[kt + 32 + quad * 8];
    abv[3] = *(const float4*)&abrow[kt + 32 + quad * 8 + 4];
    // ds_write staged K/V (tile t) into buf[cur]
#pragma unroll
    for (int u = 0; u < 4; ++u)
      *(short8*)&Ks[cur][kr_][kc_ + u * 8] = krg[u];
#pragma unroll
    for (int u = 0; u < 4; ++u)
      *(short8*)&VTs[cur][vr_][vc_ + u * 8] = vrg[u];
    __syncthreads();  // BARRIER1: K/V(t) visible; prev Ps reads drained
    if (t + 1 < SEQ / 64) {  // prefetch t+1 (flies under QK/exp/PV)
      const unsigned short* kp = kbase + (size_t)(kt + 64) * ATT;
      const unsigned short* vp = vbase + (kt + 64);
#pragma unroll
      for (int u = 0; u < 4; ++u) krg[u] = *(const short8*)&kp[u * 8];
#pragma unroll
      for (int u = 0; u < 4; ++u) vrg[u] = *(const short8*)&vp[u * 8];
    }
    // ---- QK^T: this wave covers keys [wh*32, wh*32+32)
    f32x4 sc[2];
    sc[0] = (f32x4)0.f; sc[1] = (f32x4)0.f;
#pragma unroll
    for (int nt = 0; nt < 2; ++nt) {
#pragma unroll
      for (int ks = 0; ks < 4; ++ks) {
        const short8 bF = *(const short8*)&Ks[cur][wh * 32 + nt * 16 + l16][ks * 32 + quad * 8];
        sc[nt] = __builtin_amdgcn_mfma_f32_16x16x32_bf16(aF[ks], bF, sc[nt], 0, 0, 0);
      }
    }
    // ---- p = exp(s), partial l, write P slab
#pragma unroll
    for (int nt = 0; nt < 2; ++nt) {
#pragma unroll
      for (int reg = 0; reg < 4; ++reg) {
        const float p = __expf(sc[nt][reg]);
        l_r[reg] += p;
        Ps[wq_ + quad * 4 + reg][wh * 32 + nt * 16 + l16] = f2bf(p);
      }
    }
    __syncthreads();  // BARRIER2: both key-halves of Ps complete
    // ---- PV + bias@V: this wave covers a-cols [wh*64, wh*64+64)
#pragma unroll
    for (int ks = 0; ks < 2; ++ks) {
      const short8 pF = *(const short8*)&Ps[wq_ + l16][ks * 32 + quad * 8];
      short8 bB;
      {
        const float4 u0 = abv[ks * 2], u1 = abv[ks * 2 + 1];
        bB[0] = (short)f2bf(u0.x); bB[1] = (short)f2bf(u0.y);
        bB[2] = (short)f2bf(u0.z); bB[3] = (short)f2bf(u0.w);
        bB[4] = (short)f2bf(u1.x); bB[5] = (short)f2bf(u1.y);
        bB[6] = (short)f2bf(u1.z); bB[7] = (short)f2bf(u1.w);
      }
#pragma unroll
      for (int at = 0; at < 4; ++at) {
        const short8 vF = *(const short8*)&VTs[cur][wh * 64 + at * 16 + l16][ks * 32 + quad * 8];
        o[at]  = __builtin_amdgcn_mfma_f32_16x16x32_bf16(pF, vF, o[at], 0, 0, 0);
        o2[at] = __builtin_amdgcn_mfma_f32_16x16x32_bf16(bB, vF, o2[at], 0, 0, 0);
      }
    }
  }
  // ---- l: reduce across l16 lanes, then combine the two key-half waves
#pragma unroll
  for (int reg = 0; reg < 4; ++reg) {
    float l = l_r[reg];
    l += __shfl_xor(l, 1, 64);
    l += __shfl_xor(l, 2, 64);
    l += __shfl_xor(l, 4, 64);
    l += __shfl_xor(l, 8, 64);
    l_r[reg] = l;
  }
  if (l16 == 0) {
#pragma unroll
    for (int reg = 0; reg < 4; ++reg)
      Ls[wh * 32 + wq_ + quad * 4 + reg] = l_r[reg];
  }
  __syncthreads();
  float inv_l[4];
#pragma unroll
  for (int reg = 0; reg < 4; ++reg) {
    const int row = wq_ + quad * 4 + reg;
    inv_l[reg] = 1.0f / (Ls[row] + Ls[32 + row]);
  }
#pragma unroll
  for (int at = 0; at < 4; ++at) {
    const int col = vi * ATT + wh * 64 + at * 16 + l16;
#pragma unroll
    for (int reg = 0; reg < 4; ++reg) {
      const int row = q0 + wq_ + quad * 4 + reg;
      xbf[(size_t)row * HID + col] = f2bf(o[at][reg] * inv_l[reg] + o2[at][reg]);
    }
  }
}

// ---------------------------------------------------------------------------
// Out projection: out[2048][1024] = xbf[2048][1024](bf16) @ wo + bo  (fp32)
// grid (32, 8), m-tile 64, n-tile 128, K=1024.  Min-2-phase pipelined.
// ---------------------------------------------------------------------------
__global__ __launch_bounds__(256)
void outproj_gemm(const unsigned short* __restrict__ A,
                  const unsigned short* __restrict__ B,  // woT [n][k]
                  const float* __restrict__ bias, float* __restrict__ out) {
  __shared__ alignas(16) unsigned short As[2][64][72];
  __shared__ alignas(16) unsigned short Bs[2][128][72];
  const int tid = threadIdx.x;
  const int m0 = blockIdx.x * 64;
  const int n0 = blockIdx.y * 128;
  const int w = tid >> 6, lane = tid & 63;
  const int l16 = lane & 15, quad = lane >> 4;
  const int ar = tid >> 2, ac = (tid & 3) * 16;
  const int br = tid >> 1, bc = (tid & 1) * 32;
  const unsigned short* abase = &A[(size_t)(m0 + ar) * HID + ac];
  const unsigned short* bbase = &B[(size_t)(n0 + br) * HID + bc];

  f32x4 acc[8];
#pragma unroll
  for (int i = 0; i < 8; ++i) acc[i] = (f32x4)0.f;

  // prologue: issue loads for k-tile 0
  short8 arg0, arg1, brg[4];
  arg0 = *(const short8*)&abase[0];
  arg1 = *(const short8*)&abase[8];
#pragma unroll
  for (int u = 0; u < 4; ++u) brg[u] = *(const short8*)&bbase[u * 8];

  for (int kk = 0; kk < HID / 64; ++kk) {
    const int cur = kk & 1;
    // write staged regs into LDS buf[cur]
    *(short8*)&As[cur][ar][ac]     = arg0;
    *(short8*)&As[cur][ar][ac + 8] = arg1;
#pragma unroll
    for (int u = 0; u < 4; ++u)
      *(short8*)&Bs[cur][br][bc + u * 8] = brg[u];
    __syncthreads();
    // issue loads for k-tile kk+1
    if (kk + 1 < HID / 64) {
      const unsigned short* ap = abase + (kk + 1) * 64;
      const unsigned short* bp = bbase + (kk + 1) * 64;
      arg0 = *(const short8*)&ap[0];
      arg1 = *(const short8*)&ap[8];
#pragma unroll
      for (int u = 0; u < 4; ++u) brg[u] = *(const short8*)&bp[u * 8];
    }
    // compute from buf[cur]
#pragma unroll
    for (int ks = 0; ks < 2; ++ks) {
      short8 af = *(const short8*)&As[cur][w * 16 + l16][ks * 32 + quad * 8];
#pragma unroll
      for (int nt = 0; nt < 8; ++nt) {
        short8 bf = *(const short8*)&Bs[cur][nt * 16 + l16][ks * 32 + quad * 8];
        acc[nt] = __builtin_amdgcn_mfma_f32_16x16x32_bf16(af, bf, acc[nt], 0, 0, 0);
      }
    }
  }
#pragma unroll
  for (int nt = 0; nt < 8; ++nt) {
    const int col = n0 + nt * 16 + l16;
    const float bvv = bias[col];
#pragma unroll
    for (int reg = 0; reg < 4; ++reg) {
      const int row = m0 + w * 16 + quad * 4 + reg;
      out[(size_t)row * HID + col] = acc[nt][reg] + bvv;
    }
  }
}

// ---------------------------------------------------------------------------
extern "C" void kernel_launch(void* const* d_in, const int* in_sizes, int n_in,
                              void* d_out, int out_size, void* d_ws, size_t ws_size,
                              hipStream_t stream) {
  const float* q   = (const float*)d_in[0];
  const float* k   = (const float*)d_in[1];
  const float* v   = (const float*)d_in[2];
  const float* ab  = (const float*)d_in[3];
  const float* wq  = (const float*)d_in[4];
  const float* bq  = (const float*)d_in[5];
  const float* wk  = (const float*)d_in[6];
  const float* bk  = (const float*)d_in[7];
  const float* wv  = (const float*)d_in[8];
  const float* bv  = (const float*)d_in[9];
  const float* wo  = (const float*)d_in[10];
  const float* bo  = (const float*)d_in[11];
  float* out = (float*)d_out;

  char* ws = (char*)d_ws;
  const size_t PROJ_B = (size_t)VIEWS * SEQ * ATT * 2;  // 4 MB bf16
  unsigned short* qh  = (unsigned short*)(ws);
  unsigned short* kh  = (unsigned short*)(ws + PROJ_B);
  unsigned short* vhT = (unsigned short*)(ws + 2 * PROJ_B);
  unsigned short* xbf = (unsigned short*)(ws + 3 * PROJ_B);
  char* wbase = ws + 4 * PROJ_B;
  unsigned short* wqT = (unsigned short*)(wbase);
  unsigned short* wkT = (unsigned short*)(wbase + 262144);
  unsigned short* wvT = (unsigned short*)(wbase + 2 * 262144);
  unsigned short* woT = (unsigned short*)(wbase + 3 * 262144);

  dim3 blk(256);
  transpose_qkvw<<<dim3(2, 16, 3), blk, 0, stream>>>(wq, wk, wv, wqT, wkT, wvT);
  transpose_cvt_f32_bf16<<<dim3(16, 16), blk, 0, stream>>>(wo, woT, HID, HID);
  qkv_proj<<<dim3(512, 1, 3), blk, 0, stream>>>(q, k, v, wqT, wkT, wvT,
                                                bq, bk, bv, qh, kh, vhT);
  flash_fused<<<dim3(VIEWS, SEQ / 32), blk, 0, stream>>>(qh, kh, vhT, ab, xbf);
  outproj_gemm<<<dim3(SEQ / 64, HID / 128), blk, 0, stream>>>(xbf, woT, bo, out);
}

// Round 6
// 412.012 us; speedup vs baseline: 1.1795x; 1.0380x over previous
//
#include <hip/hip_runtime.h>
#include <math.h>

#define VIEWS 8
#define SEQ 2048
#define HID 1024
#define ATT 128
#define QSCALE 0.08838834764831845f  // 128^-0.5

typedef __attribute__((ext_vector_type(8))) short short8;
typedef __attribute__((ext_vector_type(4))) float f32x4;

#define GLOAD_LDS16(g, l)                                                     \
  __builtin_amdgcn_global_load_lds(                                           \
      (const __attribute__((address_space(1))) unsigned int*)(g),             \
      (__attribute__((address_space(3))) unsigned int*)(l), 16, 0, 0)

__device__ __forceinline__ unsigned short f2bf(float f) {
  union { float f; unsigned u; } a; a.f = f;
  unsigned r = a.u + 0x7FFF + ((a.u >> 16) & 1);  // RNE
  return (unsigned short)(r >> 16);
}

// ---------------------------------------------------------------------------
// Transpose + convert fp32 [R][C] -> bf16 [C][R].  R,C multiples of 64.
// ---------------------------------------------------------------------------
__global__ __launch_bounds__(256)
void transpose_cvt_f32_bf16(const float* __restrict__ in,
                            unsigned short* __restrict__ out, int R, int C) {
  __shared__ alignas(16) unsigned short T[64][72];
  const int tid = threadIdx.x;
  const int r0 = blockIdx.y * 64, c0 = blockIdx.x * 64;
  const int tr = tid >> 2, tc = (tid & 3) * 16;
#pragma unroll
  for (int u = 0; u < 4; ++u) {
    float4 t = *(const float4*)&in[(size_t)(r0 + tr) * C + c0 + tc + u * 4];
    T[tc + u * 4 + 0][tr] = f2bf(t.x);
    T[tc + u * 4 + 1][tr] = f2bf(t.y);
    T[tc + u * 4 + 2][tr] = f2bf(t.z);
    T[tc + u * 4 + 3][tr] = f2bf(t.w);
  }
  __syncthreads();
  const int oc = tid >> 2, orr = (tid & 3) * 16;
#pragma unroll
  for (int u = 0; u < 2; ++u)
    *(short8*)&out[(size_t)(c0 + oc) * R + r0 + orr + u * 8] =
        *(const short8*)&T[oc][orr + u * 8];
}

// Batched variant for wq/wk/wv (z selects). R=1024, C=128. grid (2,16,3).
__global__ __launch_bounds__(256)
void transpose_qkvw(const float* __restrict__ wq, const float* __restrict__ wk,
                    const float* __restrict__ wv, unsigned short* __restrict__ oq,
                    unsigned short* __restrict__ ok, unsigned short* __restrict__ ov) {
  __shared__ alignas(16) unsigned short T[64][72];
  const int z = blockIdx.z;
  const float* in = (z == 0) ? wq : (z == 1) ? wk : wv;
  unsigned short* out = (z == 0) ? oq : (z == 1) ? ok : ov;
  const int R = HID, C = ATT;
  const int tid = threadIdx.x;
  const int r0 = blockIdx.y * 64, c0 = blockIdx.x * 64;
  const int tr = tid >> 2, tc = (tid & 3) * 16;
#pragma unroll
  for (int u = 0; u < 4; ++u) {
    float4 t = *(const float4*)&in[(size_t)(r0 + tr) * C + c0 + tc + u * 4];
    T[tc + u * 4 + 0][tr] = f2bf(t.x);
    T[tc + u * 4 + 1][tr] = f2bf(t.y);
    T[tc + u * 4 + 2][tr] = f2bf(t.z);
    T[tc + u * 4 + 3][tr] = f2bf(t.w);
  }
  __syncthreads();
  const int oc = tid >> 2, orr = (tid & 3) * 16;
#pragma unroll
  for (int u = 0; u < 2; ++u)
    *(short8*)&out[(size_t)(c0 + oc) * R + r0 + orr + u * 8] =
        *(const short8*)&T[oc][orr + u * 8];
}

// ---------------------------------------------------------------------------
// Fused QKV projection — global_load_lds staging with XOR bank swizzle.
//   LDS dest is linear (DMA requirement); the swizzle is applied by
//   pre-permuting the per-lane GLOBAL source address within each row
//   (granule ^= row&7, 16B granules) and XOR-ing the same key on ds_read.
//   This turns the 16-way fragment-read conflict into 2-way (free).
// m-tile 32, 4 waves = 2m x 2n; LDS 48 KB; grid (512,1,3).
// ---------------------------------------------------------------------------
__global__ __launch_bounds__(256, 2)
void qkv_proj(const float* __restrict__ q, const float* __restrict__ k,
              const float* __restrict__ v, const unsigned short* __restrict__ wqT,
              const unsigned short* __restrict__ wkT,
              const unsigned short* __restrict__ wvT,
              const float* __restrict__ bq, const float* __restrict__ bk,
              const float* __restrict__ bv, unsigned short* __restrict__ qh,
              unsigned short* __restrict__ kh, unsigned short* __restrict__ vhT) {
  __shared__ alignas(16) float Af[2][32][64];
  __shared__ alignas(16) unsigned short Bf[2][128][64];
  const int z = blockIdx.z;
  const float* A = (z == 0) ? q : (z == 1) ? k : v;
  const unsigned short* B = (z == 0) ? wqT : (z == 1) ? wkT : wvT;
  const float* bias = (z == 0) ? bq : (z == 1) ? bk : bv;
  const float scale = (z == 0) ? QSCALE : 1.0f;
  const int tid = threadIdx.x;
  const int w = tid >> 6, lane = tid & 63;
  const int l16 = lane & 15, quad = lane >> 4;
  const int m0 = blockIdx.x * 32;
  const int wm = (w & 1) * 16;     // wave's 16-row q-slab
  const int n0 = (w >> 1) * 64;    // wave's 64-col half of ATT

  // A DMA chunks: chunk c = w*2+j covers rows c*4..c*4+3 (1 KB).
  //   lane -> row r = c*4+(lane>>4), LDS slot p = lane&15 (16B granule).
  //   source granule = p ^ (r&7)   (inverse swizzle at the source)
  const float* ag[2];
#pragma unroll
  for (int j = 0; j < 2; ++j) {
    const int c = w * 2 + j;
    const int r = c * 4 + (lane >> 4);
    const int sg = (lane & 15) ^ (r & 7);
    ag[j] = &A[(size_t)(m0 + r) * HID + sg * 4];
  }
  // B DMA chunks: chunk c = w*4+j covers rows c*8..c*8+7 (1 KB).
  //   lane -> row r = c*8+(lane>>3), slot p = lane&7; source granule p^(r&7).
  const unsigned short* bg[4];
#pragma unroll
  for (int j = 0; j < 4; ++j) {
    const int c = w * 4 + j;
    const int r = c * 8 + (lane >> 3);
    const int sg = (lane & 7) ^ (r & 7);
    bg[j] = &B[(size_t)r * HID + sg * 8];
  }

  f32x4 acc[4];
#pragma unroll
  for (int i = 0; i < 4; ++i) acc[i] = (f32x4)0.f;

#define QKV_STAGE(nxt, k0)                                                    \
  do {                                                                        \
    _Pragma("unroll") for (int j = 0; j < 2; ++j)                             \
        GLOAD_LDS16(ag[j] + (k0), &Af[nxt][(w * 2 + j) * 4][0]);              \
    _Pragma("unroll") for (int j = 0; j < 4; ++j)                             \
        GLOAD_LDS16(bg[j] + (k0), &Bf[nxt][(w * 4 + j) * 8][0]);              \
  } while (0)

  QKV_STAGE(0, 0);
  int cur = 0;
  const int akey = l16 & 7;  // swizzle key for all fragment rows (row&7==l16&7)
  for (int kk = 0; kk < HID / 64; ++kk) {
    __syncthreads();  // drains DMA for buf[cur] (and prev ds_reads)
    if (kk + 1 < HID / 64) QKV_STAGE(cur ^ 1, (kk + 1) * 64);
    // A fragments: fp32 granules {quad*2, quad*2+1, quad*2+8, quad*2+9},
    // each fetched from swizzled slot g^akey.
    const float4 a0 = *(const float4*)&Af[cur][wm + l16][((quad * 2)     ^ akey) * 4];
    const float4 a1 = *(const float4*)&Af[cur][wm + l16][((quad * 2 + 1) ^ akey) * 4];
    const float4 a2 = *(const float4*)&Af[cur][wm + l16][((quad * 2 + 8) ^ akey) * 4];
    const float4 a3 = *(const float4*)&Af[cur][wm + l16][((quad * 2 + 9) ^ akey) * 4];
    short8 af0, af1;
    af0[0] = (short)f2bf(a0.x); af0[1] = (short)f2bf(a0.y);
    af0[2] = (short)f2bf(a0.z); af0[3] = (short)f2bf(a0.w);
    af0[4] = (short)f2bf(a1.x); af0[5] = (short)f2bf(a1.y);
    af0[6] = (short)f2bf(a1.z); af0[7] = (short)f2bf(a1.w);
    af1[0] = (short)f2bf(a2.x); af1[1] = (short)f2bf(a2.y);
    af1[2] = (short)f2bf(a2.z); af1[3] = (short)f2bf(a2.w);
    af1[4] = (short)f2bf(a3.x); af1[5] = (short)f2bf(a3.y);
    af1[6] = (short)f2bf(a3.z); af1[7] = (short)f2bf(a3.w);
#pragma unroll
    for (int nt = 0; nt < 4; ++nt) {
      const int brow = n0 + nt * 16 + l16;
      const short8 b0 = *(const short8*)&Bf[cur][brow][((quad)     ^ akey) * 8];
      const short8 b1 = *(const short8*)&Bf[cur][brow][((quad + 4) ^ akey) * 8];
      acc[nt] = __builtin_amdgcn_mfma_f32_16x16x32_bf16(af0, b0, acc[nt], 0, 0, 0);
      acc[nt] = __builtin_amdgcn_mfma_f32_16x16x32_bf16(af1, b1, acc[nt], 0, 0, 0);
    }
    cur ^= 1;
  }
#undef QKV_STAGE

  if (z < 2) {
    unsigned short* outp = (z == 0) ? qh : kh;
#pragma unroll
    for (int nt = 0; nt < 4; ++nt) {
      const int col = n0 + nt * 16 + l16;
      const float bvv = bias[col];
#pragma unroll
      for (int reg = 0; reg < 4; ++reg) {
        const int row = m0 + wm + quad * 4 + reg;
        outp[(size_t)row * ATT + col] = f2bf((acc[nt][reg] + bvv) * scale);
      }
    }
  } else {
    // transposed store: vhT[vi][a][s]; 4 consecutive rows share vi (32 | 2048)
    const int gr = m0 + wm + quad * 4;
    const int vi = gr >> 11, s = gr & (SEQ - 1);
#pragma unroll
    for (int nt = 0; nt < 4; ++nt) {
      const int col = n0 + nt * 16 + l16;
      const float bvv = bias[col];
      ushort4 pk;
      pk.x = f2bf(acc[nt][0] + bvv);
      pk.y = f2bf(acc[nt][1] + bvv);
      pk.z = f2bf(acc[nt][2] + bvv);
      pk.w = f2bf(acc[nt][3] + bvv);
      *(ushort4*)&vhT[((size_t)vi * ATT + col) * SEQ + s] = pk;
    }
  }
}

// ---------------------------------------------------------------------------
// Fused flash attention + post-softmax-bias@V, min-2-phase pipelined
// (reverted to the verified 64-row version: R4/R5 A/B showed the 32-row
//  variant costs ~16 µs from doubled K/V re-staging).
// grid (VIEWS, SEQ/64); LDS = 96 KB -> 1 block/CU.
// ---------------------------------------------------------------------------
__global__ __launch_bounds__(256, 1)
void flash_fused(const unsigned short* __restrict__ qh,
                 const unsigned short* __restrict__ kh,
                 const unsigned short* __restrict__ vhT,
                 const float* __restrict__ ab,
                 unsigned short* __restrict__ xbf) {
  __shared__ alignas(16) unsigned short Qs[64][136];
  __shared__ alignas(16) unsigned short Ks[2][64][136];
  __shared__ alignas(16) unsigned short VTs[2][128][72];
  __shared__ alignas(16) unsigned short Ps[64][72];
  const int tid = threadIdx.x;
  const int vi = blockIdx.x;
  const int q0 = blockIdx.y * 64;
  const int w = tid >> 6, lane = tid & 63;
  const int l16 = lane & 15, quad = lane >> 4;
  const int wb = w * 16;

  // staging coordinates
  const int kr_ = tid >> 2, kc_ = (tid & 3) * 32;   // K tile [64 keys][128]
  const int vr_ = tid >> 1, vc_ = (tid & 1) * 32;   // V^T tile [128 a][64 keys]
  const unsigned short* kbase = &kh[((size_t)vi * SEQ + kr_) * ATT + kc_];
  const unsigned short* vbase = &vhT[((size_t)vi * ATT + vr_) * SEQ + vc_];

  {  // stage Q tile once
    const int r = tid >> 2, c = (tid & 3) * 32;
    const unsigned short* src = &qh[((size_t)vi * SEQ + q0 + r) * ATT + c];
#pragma unroll
    for (int u = 0; u < 4; ++u)
      *(short8*)&Qs[r][c + u * 8] = *(const short8*)&src[u * 8];
  }

  // prologue: issue K/V loads for tile 0 into regs
  short8 krg[4], vrg[4];
#pragma unroll
  for (int u = 0; u < 4; ++u) krg[u] = *(const short8*)&kbase[u * 8];
#pragma unroll
  for (int u = 0; u < 4; ++u) vrg[u] = *(const short8*)&vbase[u * 8];

  __syncthreads();  // Qs visible
  short8 aF[4];
#pragma unroll
  for (int ks = 0; ks < 4; ++ks)
    aF[ks] = *(const short8*)&Qs[wb + l16][ks * 32 + quad * 8];

  float l_r[4] = {0.f, 0.f, 0.f, 0.f};
  f32x4 o[8], o2[8];
#pragma unroll
  for (int i = 0; i < 8; ++i) { o[i] = (f32x4)0.f; o2[i] = (f32x4)0.f; }

  const float* abrow = &ab[((size_t)vi * SEQ + q0 + wb + l16) * SEQ];

  for (int t = 0; t < SEQ / 64; ++t) {
    const int kt = t * 64;
    const int cur = t & 1;
    // bias fragment loads for tile t (issued early, consumed in PV phase)
    float4 abv[4];
    abv[0] = *(const float4*)&abrow[kt + quad * 8];
    abv[1] = *(const float4*)&abrow[kt + quad * 8 + 4];
    abv[2] = *(const float4*)&abrow[kt + 32 + quad * 8];
    abv[3] = *(const float4*)&abrow[kt + 32 + quad * 8 + 4];
    // ---- write staged regs (tile t) into LDS buf[cur]
#pragma unroll
    for (int u = 0; u < 4; ++u)
      *(short8*)&Ks[cur][kr_][kc_ + u * 8] = krg[u];
#pragma unroll
    for (int u = 0; u < 4; ++u)
      *(short8*)&VTs[cur][vr_][vc_ + u * 8] = vrg[u];
    __syncthreads();
    // ---- issue K/V loads for tile t+1 (fly under the MFMA phase)
    if (t + 1 < SEQ / 64) {
      const unsigned short* kp = kbase + (size_t)(kt + 64) * ATT;
      const unsigned short* vp = vbase + (kt + 64);
#pragma unroll
      for (int u = 0; u < 4; ++u) krg[u] = *(const short8*)&kp[u * 8];
#pragma unroll
      for (int u = 0; u < 4; ++u) vrg[u] = *(const short8*)&vp[u * 8];
    }
    // ---- QK^T
    f32x4 sc[4];
#pragma unroll
    for (int i = 0; i < 4; ++i) sc[i] = (f32x4)0.f;
#pragma unroll
    for (int nt = 0; nt < 4; ++nt) {
#pragma unroll
      for (int ks = 0; ks < 4; ++ks) {
        short8 bF = *(const short8*)&Ks[cur][nt * 16 + l16][ks * 32 + quad * 8];
        sc[nt] = __builtin_amdgcn_mfma_f32_16x16x32_bf16(aF[ks], bF, sc[nt], 0, 0, 0);
      }
    }
    // ---- p = exp(s); accumulate partial l per lane (no shuffles)
#pragma unroll
    for (int nt = 0; nt < 4; ++nt) {
#pragma unroll
      for (int reg = 0; reg < 4; ++reg) {
        float p = __expf(sc[nt][reg]);
        l_r[reg] += p;
        Ps[wb + quad * 4 + reg][nt * 16 + l16] = f2bf(p);
      }
    }
    // ---- PV + bias@V sharing V fragments
#pragma unroll
    for (int ks = 0; ks < 2; ++ks) {
      short8 pF = *(const short8*)&Ps[wb + l16][ks * 32 + quad * 8];
      short8 bB;
      {
        const float4 u0 = abv[ks * 2], u1 = abv[ks * 2 + 1];
        bB[0] = (short)f2bf(u0.x); bB[1] = (short)f2bf(u0.y);
        bB[2] = (short)f2bf(u0.z); bB[3] = (short)f2bf(u0.w);
        bB[4] = (short)f2bf(u1.x); bB[5] = (short)f2bf(u1.y);
        bB[6] = (short)f2bf(u1.z); bB[7] = (short)f2bf(u1.w);
      }
#pragma unroll
      for (int at = 0; at < 8; ++at) {
        short8 vF = *(const short8*)&VTs[cur][at * 16 + l16][ks * 32 + quad * 8];
        o[at]  = __builtin_amdgcn_mfma_f32_16x16x32_bf16(pF, vF, o[at], 0, 0, 0);
        o2[at] = __builtin_amdgcn_mfma_f32_16x16x32_bf16(bB, vF, o2[at], 0, 0, 0);
      }
    }
  }
  // final l reduction across the 16 l16-lanes, then epilogue
  float inv_l[4];
#pragma unroll
  for (int reg = 0; reg < 4; ++reg) {
    float l = l_r[reg];
    l += __shfl_xor(l, 1, 64);
    l += __shfl_xor(l, 2, 64);
    l += __shfl_xor(l, 4, 64);
    l += __shfl_xor(l, 8, 64);
    inv_l[reg] = 1.0f / l;
  }
#pragma unroll
  for (int at = 0; at < 8; ++at) {
    const int col = vi * ATT + at * 16 + l16;
#pragma unroll
    for (int reg = 0; reg < 4; ++reg) {
      const int row = q0 + wb + quad * 4 + reg;
      xbf[(size_t)row * HID + col] = f2bf(o[at][reg] * inv_l[reg] + o2[at][reg]);
    }
  }
}

// ---------------------------------------------------------------------------
// Out projection: out[2048][1024] = xbf[2048][1024](bf16) @ wo + bo  (fp32)
// grid (32, 8), m-tile 64, n-tile 128, K=1024.  Min-2-phase pipelined.
// ---------------------------------------------------------------------------
__global__ __launch_bounds__(256)
void outproj_gemm(const unsigned short* __restrict__ A,
                  const unsigned short* __restrict__ B,  // woT [n][k]
                  const float* __restrict__ bias, float* __restrict__ out) {
  __shared__ alignas(16) unsigned short As[2][64][72];
  __shared__ alignas(16) unsigned short Bs[2][128][72];
  const int tid = threadIdx.x;
  const int m0 = blockIdx.x * 64;
  const int n0 = blockIdx.y * 128;
  const int w = tid >> 6, lane = tid & 63;
  const int l16 = lane & 15, quad = lane >> 4;
  const int ar = tid >> 2, ac = (tid & 3) * 16;
  const int br = tid >> 1, bc = (tid & 1) * 32;
  const unsigned short* abase = &A[(size_t)(m0 + ar) * HID + ac];
  const unsigned short* bbase = &B[(size_t)(n0 + br) * HID + bc];

  f32x4 acc[8];
#pragma unroll
  for (int i = 0; i < 8; ++i) acc[i] = (f32x4)0.f;

  // prologue: issue loads for k-tile 0
  short8 arg0, arg1, brg[4];
  arg0 = *(const short8*)&abase[0];
  arg1 = *(const short8*)&abase[8];
#pragma unroll
  for (int u = 0; u < 4; ++u) brg[u] = *(const short8*)&bbase[u * 8];

  for (int kk = 0; kk < HID / 64; ++kk) {
    const int cur = kk & 1;
    // write staged regs into LDS buf[cur]
    *(short8*)&As[cur][ar][ac]     = arg0;
    *(short8*)&As[cur][ar][ac + 8] = arg1;
#pragma unroll
    for (int u = 0; u < 4; ++u)
      *(short8*)&Bs[cur][br][bc + u * 8] = brg[u];
    __syncthreads();
    // issue loads for k-tile kk+1
    if (kk + 1 < HID / 64) {
      const unsigned short* ap = abase + (kk + 1) * 64;
      const unsigned short* bp = bbase + (kk + 1) * 64;
      arg0 = *(const short8*)&ap[0];
      arg1 = *(const short8*)&ap[8];
#pragma unroll
      for (int u = 0; u < 4; ++u) brg[u] = *(const short8*)&bp[u * 8];
    }
    // compute from buf[cur]
#pragma unroll
    for (int ks = 0; ks < 2; ++ks) {
      short8 af = *(const short8*)&As[cur][w * 16 + l16][ks * 32 + quad * 8];
#pragma unroll
      for (int nt = 0; nt < 8; ++nt) {
        short8 bf = *(const short8*)&Bs[cur][nt * 16 + l16][ks * 32 + quad * 8];
        acc[nt] = __builtin_amdgcn_mfma_f32_16x16x32_bf16(af, bf, acc[nt], 0, 0, 0);
      }
    }
  }
#pragma unroll
  for (int nt = 0; nt < 8; ++nt) {
    const int col = n0 + nt * 16 + l16;
    const float bvv = bias[col];
#pragma unroll
    for (int reg = 0; reg < 4; ++reg) {
      const int row = m0 + w * 16 + quad * 4 + reg;
      out[(size_t)row * HID + col] = acc[nt][reg] + bvv;
    }
  }
}

// ---------------------------------------------------------------------------
extern "C" void kernel_launch(void* const* d_in, const int* in_sizes, int n_in,
                              void* d_out, int out_size, void* d_ws, size_t ws_size,
                              hipStream_t stream) {
  const float* q   = (const float*)d_in[0];
  const float* k   = (const float*)d_in[1];
  const float* v   = (const float*)d_in[2];
  const float* ab  = (const float*)d_in[3];
  const float* wq  = (const float*)d_in[4];
  const float* bq  = (const float*)d_in[5];
  const float* wk  = (const float*)d_in[6];
  const float* bk  = (const float*)d_in[7];
  const float* wv  = (const float*)d_in[8];
  const float* bv  = (const float*)d_in[9];
  const float* wo  = (const float*)d_in[10];
  const float* bo  = (const float*)d_in[11];
  float* out = (float*)d_out;

  char* ws = (char*)d_ws;
  const size_t PROJ_B = (size_t)VIEWS * SEQ * ATT * 2;  // 4 MB bf16
  unsigned short* qh  = (unsigned short*)(ws);
  unsigned short* kh  = (unsigned short*)(ws + PROJ_B);
  unsigned short* vhT = (unsigned short*)(ws + 2 * PROJ_B);
  unsigned short* xbf = (unsigned short*)(ws + 3 * PROJ_B);
  char* wbase = ws + 4 * PROJ_B;
  unsigned short* wqT = (unsigned short*)(wbase);
  unsigned short* wkT = (unsigned short*)(wbase + 262144);
  unsigned short* wvT = (unsigned short*)(wbase + 2 * 262144);
  unsigned short* woT = (unsigned short*)(wbase + 3 * 262144);

  dim3 blk(256);
  transpose_qkvw<<<dim3(2, 16, 3), blk, 0, stream>>>(wq, wk, wv, wqT, wkT, wvT);
  transpose_cvt_f32_bf16<<<dim3(16, 16), blk, 0, stream>>>(wo, woT, HID, HID);
  qkv_proj<<<dim3(512, 1, 3), blk, 0, stream>>>(q, k, v, wqT, wkT, wvT,
                                                bq, bk, bv, qh, kh, vhT);
  flash_fused<<<dim3(VIEWS, SEQ / 64), blk, 0, stream>>>(qh, kh, vhT, ab, xbf);
  outproj_gemm<<<dim3(SEQ / 64, HID / 128), blk, 0, stream>>>(xbf, woT, bo, out);
}